// Round 6
// baseline (332.048 us; speedup 1.0000x reference)
//
#include <hip/hip_runtime.h>
#include <float.h>
#include <limits.h>

#define N_Q 8192
#define M_PTS 50000
#define DIM 128
#define KNN 10
#define NCLS 10
#define NCHUNK 8           // 8 chunks: c<5 -> 391 tiles, else 390 (3125 total)
#define CPC 8              // candidates kept per (query, chunk)
#define NCAND (NCHUNK*CPC) // 64 candidates per query
#define NSEL 16            // exact-rescored candidates per query
#define TPL 4              // per-lane-class top depth (E[loss] ~ 8e-3 over all q)
#define QPB 128            // queries per block (4 waves x 32)
#define XN4 (N_Q*DIM/4)    // 262144 float4 in x
#define YN4 (M_PTS*DIM/4)  // 1600000 float4 in y

typedef __attribute__((ext_vector_type(8))) short bf16x8;
typedef __attribute__((ext_vector_type(4))) float f32x4;
typedef unsigned int u32;
typedef unsigned short u16;

__device__ __forceinline__ int chunk_t0(int c) { return c * 390 + (c < 5 ? c : 5); }

__device__ __forceinline__ u16 rne_bf16(float f) {
    u32 u = __float_as_uint(f);
    u32 r = u + 0x7FFFu + ((u >> 16) & 1u);
    return (u16)(r >> 16);
}

// ---------------------------------------------------------------------------
// Prep: bf16-convert x and y; fold y2 = ||y_j||^2 out of the same y load.
// ---------------------------------------------------------------------------
__global__ __launch_bounds__(256) void prep_kernel(
    const float4* __restrict__ x4, const float4* __restrict__ y4,
    ushort4* __restrict__ xb4, ushort4* __restrict__ yb4,
    float* __restrict__ y2) {
    int t = blockIdx.x * 256 + threadIdx.x;
    if (t < XN4) {
        float4 v = x4[t];
        ushort4 o;
        o.x = rne_bf16(v.x); o.y = rne_bf16(v.y);
        o.z = rne_bf16(v.z); o.w = rne_bf16(v.w);
        xb4[t] = o;
    } else {
        int j = t - XN4;
        float4 v = y4[j];
        ushort4 o;
        o.x = rne_bf16(v.x); o.y = rne_bf16(v.y);
        o.z = rne_bf16(v.z); o.w = rne_bf16(v.w);
        yb4[j] = o;
        float p = v.x * v.x + v.y * v.y + v.z * v.z + v.w * v.w;
        #pragma unroll
        for (int off = 16; off > 0; off >>= 1) p += __shfl_xor(p, off, 64);
        if ((j & 31) == 0) y2[j >> 5] = p;
    }
}

// ---------------------------------------------------------------------------
// Filter: bf16 MFMA, LDS double-buffered B tiles, software-pipelined insert:
// the score-extract+top-4-insert of tile t issues in the same body as the
// MFMAs of tile t+1, so a wave's VALU overlaps its own matrix-pipe time.
// launch_bounds(256,2): 256-reg budget so ts[] stays in arch VGPRs (at
// (256,3)/(256,4) the unified-RF allocator put ts in AGPRs -> ~64
// v_accvgpr_read/write per iter = the round-4/5 VALU blowup).
// Grid 8x64 = 512 = exactly 2 blocks/CU; chunk pinned per XCD (1.6 MB L2 set).
// ---------------------------------------------------------------------------
__global__ __launch_bounds__(256, 2) void knn_filter(
    const u16* __restrict__ xb, const u16* __restrict__ yb,
    const float* __restrict__ y2, u32* __restrict__ ckey) {
    const int lane = threadIdx.x & 63;
    const int wid  = threadIdx.x >> 6;      // wave 0..3
    const int g    = lane >> 4;             // k-group 0..3
    const int nrow = lane & 15;             // point-in-tile (B col / C col)
    const int chunk = blockIdx.x;           // 0..7 -> XCD pin via id%8
    const int qb    = blockIdx.y;
    const int t0 = chunk_t0(chunk);
    const int tn = 390 + (chunk < 5 ? 1 : 0);
    const int p0 = t0 * 16;
    const int qw = qb * QPB + wid * 32;

    // A fragments: 2 sets x 4 frags (k = 32*b + 8*g + e), 32 VGPRs
    bf16x8 a[2][4];
    #pragma unroll
    for (int s = 0; s < 2; ++s) {
        const u16* xr = xb + (size_t)(qw + s * 16 + nrow) * DIM + g * 8;
        #pragma unroll
        for (int b = 0; b < 4; ++b) a[s][b] = *(const bf16x8*)(xr + b * 32);
    }

    float ts[8][TPL];
    #pragma unroll
    for (int r = 0; r < 8; ++r)
        #pragma unroll
        for (int l = 0; l < TPL; ++l) ts[r][l] = FLT_MAX;

    __shared__ u32 smem[QPB * 65];          // 33280 B; bufs overlay the front
    u32* buf0 = smem;
    u32* buf1 = smem + 1024;

    // B-frag LDS slots (hoisted): slot (g+4b)^nrow holds global chunk g+4b
    const int sl0 = (((g + 0)  ^ nrow) & 15) * 4;
    const int sl1 = (((g + 4)  ^ nrow) & 15) * 4;
    const int sl2 = (((g + 8)  ^ nrow) & 15) * 4;
    const int sl3 = (((g + 12) ^ nrow) & 15) * 4;

    // Stage mapping: lane l -> row wid*4+(l>>4), slot (l&15), global chunk
    // (l&15)^row (global_load_lds places lane l at wavebase + l*16 B).
    const int srow = wid * 4 + (lane >> 4);
    const int schunk = (lane & 15) ^ srow;
    const u16* ysrc = yb + (size_t)(p0 + srow) * DIM + schunk * 8;

    typedef const __attribute__((address_space(1))) void* gp1;
    typedef __attribute__((address_space(3))) void* lp3;

    auto mfma8 = [&](const u32* buf, f32x4& o0, f32x4& o1) {
        bf16x8 b0 = *(const bf16x8*)(buf + nrow * 64 + sl0);
        bf16x8 b1 = *(const bf16x8*)(buf + nrow * 64 + sl1);
        bf16x8 b2 = *(const bf16x8*)(buf + nrow * 64 + sl2);
        bf16x8 b3 = *(const bf16x8*)(buf + nrow * 64 + sl3);
        o0 = {0.f, 0.f, 0.f, 0.f};
        o1 = {0.f, 0.f, 0.f, 0.f};
        o0 = __builtin_amdgcn_mfma_f32_16x16x32_bf16(a[0][0], b0, o0, 0, 0, 0);
        o0 = __builtin_amdgcn_mfma_f32_16x16x32_bf16(a[0][1], b1, o0, 0, 0, 0);
        o0 = __builtin_amdgcn_mfma_f32_16x16x32_bf16(a[0][2], b2, o0, 0, 0, 0);
        o0 = __builtin_amdgcn_mfma_f32_16x16x32_bf16(a[0][3], b3, o0, 0, 0, 0);
        o1 = __builtin_amdgcn_mfma_f32_16x16x32_bf16(a[1][0], b0, o1, 0, 0, 0);
        o1 = __builtin_amdgcn_mfma_f32_16x16x32_bf16(a[1][1], b1, o1, 0, 0, 0);
        o1 = __builtin_amdgcn_mfma_f32_16x16x32_bf16(a[1][2], b2, o1, 0, 0, 0);
        o1 = __builtin_amdgcn_mfma_f32_16x16x32_bf16(a[1][3], b3, o1, 0, 0, 0);
    };
    auto insert8 = [&](const f32x4& A0, const f32x4& A1, float y2v, u32 rel) {
        #pragma unroll
        for (int i = 0; i < 8; ++i) {
            float av = (i < 4) ? A0[i] : A1[i - 4];
            float sc = fmaf(-2.0f, av, y2v);
            float key = __uint_as_float((__float_as_uint(sc) & 0xFFFFE000u) | rel);
            float o0 = ts[i][0], o1 = ts[i][1], o2 = ts[i][2];
            ts[i][0] = fminf(o0, key);
            ts[i][1] = __builtin_amdgcn_fmed3f(key, o0, o1);
            ts[i][2] = __builtin_amdgcn_fmed3f(key, o1, o2);
            ts[i][3] = __builtin_amdgcn_fmed3f(key, o2, ts[i][3]);
        }
    };

    // ---- prologue ----
    __builtin_amdgcn_global_load_lds((gp1)ysrc, (lp3)(buf0 + wid * 256), 16, 0, 0);
    ysrc += 16 * DIM;
    __syncthreads();
    __builtin_amdgcn_global_load_lds((gp1)ysrc, (lp3)(buf1 + wid * 256), 16, 0, 0);
    ysrc += 16 * DIM;
    const float* y2ptr = y2 + p0 + nrow;
    float y2A = y2ptr[0];                   // y2 for tile 0
    f32x4 aP0, aP1;
    mfma8(buf0, aP0, aP1);                  // tile 0
    u32 relP = (u32)nrow;
    __syncthreads();                        // tile1 ready, buf0 free
    float y2B = y2ptr[16];                  // y2 for tile 1

    // ---- pipelined main loop (2 tiles per iter) ----
    int t = 1;
    for (; t + 1 < tn; t += 2) {
        // body A: mfma tile t (buf1); insert tile t-1
        __builtin_amdgcn_global_load_lds((gp1)ysrc, (lp3)(buf0 + wid * 256), 16, 0, 0);
        ysrc += 16 * DIM;
        f32x4 aC0, aC1;
        mfma8(buf1, aC0, aC1);
        insert8(aP0, aP1, y2A, relP);
        relP += 16;
        y2A = y2ptr[32];                    // y2 for tile t+1
        __syncthreads();                    // buf0(t+1) ready, buf1 free
        // body B: mfma tile t+1 (buf0); insert tile t
        if (t + 2 < tn) {
            __builtin_amdgcn_global_load_lds((gp1)ysrc, (lp3)(buf1 + wid * 256), 16, 0, 0);
            ysrc += 16 * DIM;
        }
        mfma8(buf0, aP0, aP1);
        insert8(aC0, aC1, y2B, relP);
        relP += 16;
        y2B = y2ptr[48];                    // y2 for tile t+2 (may over-read: ws-padded)
        y2ptr += 32;
        __syncthreads();
    }
    // ---- tail ----
    if (t < tn) {                           // t == tn-1 (tn even), tile in buf1
        f32x4 aC0, aC1;
        mfma8(buf1, aC0, aC1);
        insert8(aP0, aP1, y2A, relP);
        relP += 16;
        insert8(aC0, aC1, y2B, relP);
    } else {                                // tn odd: last tile already pending
        insert8(aP0, aP1, y2A, relP);
    }
    __syncthreads();                        // all LDS reads done before merge

    // ---- merge 16 lane-classes -> per-query top-8 ----
    #pragma unroll
    for (int s = 0; s < 2; ++s)
        #pragma unroll
        for (int r = 0; r < 4; ++r) {
            int ql = wid * 32 + s * 16 + g * 4 + r;
            #pragma unroll
            for (int l = 0; l < TPL; ++l)
                smem[ql * 65 + nrow * TPL + l] = __float_as_uint(ts[s * 4 + r][l]);
        }
    __syncthreads();
    if (threadIdx.x < QPB) {
        int ql = threadIdx.x;
        float bs[CPC];
        #pragma unroll
        for (int i = 0; i < CPC; ++i) bs[i] = FLT_MAX;
        for (int e = 0; e < 16 * TPL; ++e) {      // stride-65: conflict-free
            float f = __uint_as_float(smem[ql * 65 + e]);
            #pragma unroll
            for (int p = 0; p < CPC; ++p) {
                float mn = fminf(bs[p], f);
                f = fmaxf(bs[p], f);
                bs[p] = mn;
            }
        }
        u32* dst = ckey + ((size_t)(qb * QPB + ql) * NCHUNK + chunk) * CPC;
        #pragma unroll
        for (int i = 0; i < CPC; ++i) dst[i] = __float_as_uint(bs[i]);
    }
}

// ---------------------------------------------------------------------------
// Finalize (fused select+exact+vote): one wave per query.
//  A: lane e loads candidate key e; lane 0 serially selects approx-top-16
//     (keys carry 13-bit chunk-relative index; stable = jax top_k ties).
//  B: lanes (cand = l>>2, part = l&3) rescore exactly in fp64 (32 dims each,
//     reduced with 2 shuffles).
//  C: lane 0: exact top-10 of 16 with (score,idx) tie-break, majority vote,
//     ties -> LARGEST class (reference reversed-argmax).
// ---------------------------------------------------------------------------
__global__ __launch_bounds__(256) void knn_finalize(
    const u32* __restrict__ ckey, const float* __restrict__ x,
    const float* __restrict__ y, const int* __restrict__ labels,
    int* __restrict__ out) {
    const int lane = threadIdx.x & 63;
    const int wid  = threadIdx.x >> 6;
    const int q = blockIdx.x * 4 + wid;

    __shared__ u32 skey[4][NCAND];
    __shared__ int sidx[4][NSEL];
    __shared__ double sex[4][NSEL];

    skey[wid][lane] = ckey[(size_t)q * NCAND + lane];
    __syncthreads();

    if (lane == 0) {
        float bs[NSEL]; int bi[NSEL];
        #pragma unroll
        for (int i = 0; i < NSEL; ++i) { bs[i] = FLT_MAX; bi[i] = 0; }
        for (int e = 0; e < NCAND; ++e) {
            u32 u = skey[wid][e];
            float f = __uint_as_float(u);
            if (f < bs[NSEL - 1]) {
                int c = e >> 3;
                int id = chunk_t0(c) * 16 + (int)(u & 0x1FFFu);
                #pragma unroll
                for (int p = 0; p < NSEL; ++p) {
                    bool lt = f < bs[p];
                    float nf = lt ? bs[p] : f;  int nid = lt ? bi[p] : id;
                    bs[p] = lt ? f : bs[p];     bi[p] = lt ? id : bi[p];
                    f = nf; id = nid;
                }
            }
        }
        #pragma unroll
        for (int i = 0; i < NSEL; ++i) sidx[wid][i] = bi[i];
    }
    __syncthreads();

    const int cand = lane >> 2;
    const int part = lane & 3;
    const int idx = sidx[wid][cand];
    const float* xr = x + (size_t)q * DIM + part * 32;
    const float* yr = y + (size_t)idx * DIM + part * 32;
    double dy2 = 0.0, dxy = 0.0;
    #pragma unroll 8
    for (int i = 0; i < 32; ++i) {
        double yy = (double)yr[i];
        dy2 = fma(yy, yy, dy2);
        dxy = fma((double)xr[i], yy, dxy);
    }
    double e = dy2 - 2.0 * dxy;
    e += __shfl_xor(e, 1, 64);
    e += __shfl_xor(e, 2, 64);
    if (part == 0) sex[wid][cand] = e;
    __syncthreads();

    if (lane == 0) {
        double tsv[KNN]; int ti[KNN];
        #pragma unroll
        for (int i = 0; i < KNN; ++i) { tsv[i] = 1e300; ti[i] = INT_MAX; }
        #pragma unroll
        for (int c = 0; c < NSEL; ++c) {
            double s = sex[wid][c];
            int id = sidx[wid][c];
            #pragma unroll
            for (int p = 0; p < KNN; ++p) {
                bool lt = (s < tsv[p]) || (s == tsv[p] && id < ti[p]);
                double ns = lt ? tsv[p] : s;  int nid = lt ? ti[p] : id;
                tsv[p] = lt ? s : tsv[p];     ti[p] = lt ? id : ti[p];
                s = ns; id = nid;
            }
        }
        int lab[KNN];
        #pragma unroll
        for (int i = 0; i < KNN; ++i) lab[i] = labels[ti[i]];
        int bestc = 0, bestn = -1;
        #pragma unroll
        for (int c = 0; c < NCLS; ++c) {
            int n = 0;
            #pragma unroll
            for (int i = 0; i < KNN; ++i) n += (lab[i] == c) ? 1 : 0;
            if (n >= bestn) { bestn = n; bestc = c; }   // >= : ties -> larger label
        }
        out[q] = bestc;
    }
}

// ---------------------------------------------------------------------------
extern "C" void kernel_launch(void* const* d_in, const int* in_sizes, int n_in,
                              void* d_out, int out_size, void* d_ws, size_t ws_size,
                              hipStream_t stream) {
    const float* x      = (const float*)d_in[0];
    const float* y      = (const float*)d_in[1];
    const int*   labels = (const int*)d_in[2];
    // d_in[3] is k == 10, baked in.

    char* ws = (char*)d_ws;
    size_t off = 0;
    u16* xb = (u16*)(ws + off);     off += (size_t)N_Q * DIM * 2;        //  2.10 MB
    u16* yb = (u16*)(ws + off);     off += (size_t)M_PTS * DIM * 2;      // 12.80 MB
    float* y2 = (float*)(ws + off); off += (size_t)M_PTS * 4 + 4096;     //  0.20 MB (+pad: y2 prefetch may over-read)
    u32* ckey = (u32*)(ws + off);   off += (size_t)N_Q * NCAND * 4;      //  2.10 MB
    int* out = (int*)d_out;

    prep_kernel<<<(XN4 + YN4) / 256, 256, 0, stream>>>(
        (const float4*)x, (const float4*)y, (ushort4*)xb, (ushort4*)yb, y2);
    knn_filter<<<dim3(NCHUNK, N_Q / QPB), 256, 0, stream>>>(xb, yb, y2, ckey);
    knn_finalize<<<N_Q / 4, 256, 0, stream>>>(ckey, x, y, labels, out);
}

// Round 7
// 314.834 us; speedup vs baseline: 1.0547x; 1.0547x over previous
//
#include <hip/hip_runtime.h>
#include <float.h>
#include <limits.h>

#define N_Q 8192
#define M_PTS 50000
#define DIM 128
#define KNN 10
#define NCLS 10
#define NCHUNK 16          // 16 chunks: c<5 -> 196 tiles, else 195 (3125 total)
#define CPC 8              // candidates kept per (query, chunk)
#define NCAND (NCHUNK*CPC) // 128 candidates per query
#define NSEL 16            // exact-rescored candidates per query
#define TPL 4              // per-lane-class top depth
#define QPB 128            // queries per block (4 waves x 32)
#define XN4 (N_Q*DIM/4)    // 262144 float4 in x
#define YN4 (M_PTS*DIM/4)  // 1600000 float4 in y

typedef __attribute__((ext_vector_type(8))) short bf16x8;
typedef __attribute__((ext_vector_type(4))) float f32x4;
typedef unsigned int u32;
typedef unsigned short u16;

__device__ __forceinline__ int chunk_t0(int c) { return c * 195 + (c < 5 ? c : 5); }

__device__ __forceinline__ u16 rne_bf16(float f) {
    u32 u = __float_as_uint(f);
    u32 r = u + 0x7FFFu + ((u >> 16) & 1u);
    return (u16)(r >> 16);
}

// ---------------------------------------------------------------------------
// Prep: xb = bf16(-2*x)  (the -2 of the score is folded into A so the filter
// score is the raw MFMA output); yb = bf16(y); y2 = ||y_j||^2 fp32.
// ---------------------------------------------------------------------------
__global__ __launch_bounds__(256) void prep_kernel(
    const float4* __restrict__ x4, const float4* __restrict__ y4,
    ushort4* __restrict__ xb4, ushort4* __restrict__ yb4,
    float* __restrict__ y2) {
    int t = blockIdx.x * 256 + threadIdx.x;
    if (t < XN4) {
        float4 v = x4[t];
        ushort4 o;
        o.x = rne_bf16(-2.0f * v.x); o.y = rne_bf16(-2.0f * v.y);
        o.z = rne_bf16(-2.0f * v.z); o.w = rne_bf16(-2.0f * v.w);
        xb4[t] = o;
    } else {
        int j = t - XN4;
        float4 v = y4[j];
        ushort4 o;
        o.x = rne_bf16(v.x); o.y = rne_bf16(v.y);
        o.z = rne_bf16(v.z); o.w = rne_bf16(v.w);
        yb4[j] = o;
        float p = v.x * v.x + v.y * v.y + v.z * v.z + v.w * v.w;
        #pragma unroll
        for (int off = 16; off > 0; off >>= 1) p += __shfl_xor(p, off, 64);
        if ((j & 31) == 0) y2[j >> 5] = p;
    }
}

// ---------------------------------------------------------------------------
// Filter. score(q,j) = y2[j] - 2 x_q.y_j computed ENTIRELY by MFMA: A holds
// -2x, C is initialized to y2[col] (all 4 C-regs of a lane share col=point).
// Key = v_bfi(12-bit chunk-relative index into score mantissa); per-lane-class
// top-4 via 1 fmin + 3 fmed3. 5 VALU/score total.
// LDS: 2-tile double buffers (16 KB) -> one barrier per 2 tiles; merge region
// (33 KB) overlays after the loop. (256,4) + grid 16x64=1024 = 4 blocks/CU.
// ---------------------------------------------------------------------------
__global__ __launch_bounds__(256, 4) void knn_filter(
    const u16* __restrict__ xb, const u16* __restrict__ yb,
    const float* __restrict__ y2, u32* __restrict__ ckey) {
    const int lane = threadIdx.x & 63;
    const int wid  = threadIdx.x >> 6;      // wave 0..3
    const int g    = lane >> 4;             // k-group 0..3
    const int nrow = lane & 15;             // point-in-tile (B col / C col)
    const int chunk = blockIdx.x;           // 16 chunks -> XCD pin via id%8
    const int qb    = blockIdx.y;
    const int t0 = chunk_t0(chunk);
    const int tn = 195 + (chunk < 5 ? 1 : 0);
    const int p0 = t0 * 16;
    const int qw = qb * QPB + wid * 32;

    // A fragments: 2 query-sets x 4 k-blocks (k = 32*b + 8*g + e), 32 VGPRs
    bf16x8 a[2][4];
    #pragma unroll
    for (int s = 0; s < 2; ++s) {
        const u16* xr = xb + (size_t)(qw + s * 16 + nrow) * DIM + g * 8;
        #pragma unroll
        for (int b = 0; b < 4; ++b) a[s][b] = *(const bf16x8*)(xr + b * 32);
    }

    float ts[8][TPL];
    #pragma unroll
    for (int r = 0; r < 8; ++r)
        #pragma unroll
        for (int l = 0; l < TPL; ++l) ts[r][l] = FLT_MAX;

    __shared__ u32 smem[QPB * 65];          // 33280 B; staging overlays front
    u32* bufA = smem;                       // 2 tiles: +0, +1024
    u32* bufB = smem + 2048;                // 2 tiles: +2048, +3072

    // B-frag LDS slots (hoisted): slot (g+4b)^nrow holds k-chunk g+4b
    const int sl0 = (((g + 0)  ^ nrow) & 15) * 4;
    const int sl1 = (((g + 4)  ^ nrow) & 15) * 4;
    const int sl2 = (((g + 8)  ^ nrow) & 15) * 4;
    const int sl3 = (((g + 12) ^ nrow) & 15) * 4;

    // Stage mapping: lane l -> tile-row wid*4+(l>>4), slot l&15 holds k-chunk
    // (l&15)^row (global_load_lds puts lane l at wavebase + l*16 B).
    const int srow = wid * 4 + (lane >> 4);
    const int schunk = (lane & 15) ^ srow;
    const u16* ybase = yb + (size_t)(p0 + srow) * DIM + schunk * 8;

    typedef const __attribute__((address_space(1))) void* gp1;
    typedef __attribute__((address_space(3))) void* lp3;

    auto stage1 = [&](int t, u32* dst) {    // stage tile t into dst
        __builtin_amdgcn_global_load_lds((gp1)(ybase + (size_t)t * 16 * DIM),
                                         (lp3)(dst + wid * 256), 16, 0, 0);
    };
    auto stage2 = [&](int p, u32* dst) {    // stage tiles 2p, 2p+1
        stage1(2 * p, dst);
        stage1(2 * p + 1, dst + 1024);
    };

    const float* y2p = y2 + p0 + nrow;

    auto proc1 = [&](const u32* buf, int t) {
        float y2n = y2p[t * 16];
        bf16x8 b0 = *(const bf16x8*)(buf + nrow * 64 + sl0);
        bf16x8 b1 = *(const bf16x8*)(buf + nrow * 64 + sl1);
        bf16x8 b2 = *(const bf16x8*)(buf + nrow * 64 + sl2);
        bf16x8 b3 = *(const bf16x8*)(buf + nrow * 64 + sl3);
        f32x4 acc0 = {y2n, y2n, y2n, y2n};  // y2 pre-loaded into C
        f32x4 acc1 = {y2n, y2n, y2n, y2n};
        acc0 = __builtin_amdgcn_mfma_f32_16x16x32_bf16(a[0][0], b0, acc0, 0, 0, 0);
        acc0 = __builtin_amdgcn_mfma_f32_16x16x32_bf16(a[0][1], b1, acc0, 0, 0, 0);
        acc0 = __builtin_amdgcn_mfma_f32_16x16x32_bf16(a[0][2], b2, acc0, 0, 0, 0);
        acc0 = __builtin_amdgcn_mfma_f32_16x16x32_bf16(a[0][3], b3, acc0, 0, 0, 0);
        acc1 = __builtin_amdgcn_mfma_f32_16x16x32_bf16(a[1][0], b0, acc1, 0, 0, 0);
        acc1 = __builtin_amdgcn_mfma_f32_16x16x32_bf16(a[1][1], b1, acc1, 0, 0, 0);
        acc1 = __builtin_amdgcn_mfma_f32_16x16x32_bf16(a[1][2], b2, acc1, 0, 0, 0);
        acc1 = __builtin_amdgcn_mfma_f32_16x16x32_bf16(a[1][3], b3, acc1, 0, 0, 0);
        u32 rel = (u32)(t * 16) | (u32)nrow;    // < 3136, 12 bits
        #pragma unroll
        for (int i = 0; i < 8; ++i) {
            float sc = (i < 4) ? acc0[i] : acc1[i - 4];
            // key = (sc & ~0xFFF) | rel  -> one v_bfi_b32
            float key = __uint_as_float((__float_as_uint(sc) & 0xFFFFF000u) | rel);
            float o0 = ts[i][0], o1 = ts[i][1], o2 = ts[i][2];
            ts[i][0] = fminf(o0, key);
            ts[i][1] = __builtin_amdgcn_fmed3f(key, o0, o1);
            ts[i][2] = __builtin_amdgcn_fmed3f(key, o1, o2);
            ts[i][3] = __builtin_amdgcn_fmed3f(key, o2, ts[i][3]);
        }
    };
    auto proc2 = [&](const u32* buf, int p) {
        proc1(buf, 2 * p);
        proc1(buf + 1024, 2 * p + 1);
    };

    const int npairs = tn >> 1;             // 98 or 97
    const bool odd = (tn & 1) != 0;         // 195 -> true

    stage2(0, bufA);
    __syncthreads();
    int p = 0;
    while (p + 2 <= npairs) {
        stage2(p + 1, bufB);
        proc2(bufA, p);
        __syncthreads();
        if (p + 2 < npairs) stage2(p + 2, bufA);
        else if (odd)       stage1(tn - 1, bufA);
        proc2(bufB, p + 1);
        __syncthreads();
        p += 2;
    }
    if (p < npairs) {                       // npairs odd: last pair is in bufA
        if (odd) stage1(tn - 1, bufB);
        proc2(bufA, p);
        __syncthreads();
        if (odd) proc1(bufB, tn - 1);
    } else if (odd) {                       // tail tile staged into bufA
        proc1(bufA, tn - 1);
    }
    __syncthreads();                        // staging region reuse below

    // ---- merge 16 lane-classes -> per-query sorted top-8 ----
    #pragma unroll
    for (int s = 0; s < 2; ++s)
        #pragma unroll
        for (int r = 0; r < 4; ++r) {
            int ql = wid * 32 + s * 16 + g * 4 + r;
            #pragma unroll
            for (int l = 0; l < TPL; ++l)
                smem[ql * 65 + nrow * TPL + l] = __float_as_uint(ts[s * 4 + r][l]);
        }
    __syncthreads();
    if (threadIdx.x < QPB) {
        int ql = threadIdx.x;
        float bs[CPC];
        #pragma unroll
        for (int i = 0; i < CPC; ++i) bs[i] = FLT_MAX;
        for (int e = 0; e < 16 * TPL; ++e) {      // stride-65: conflict-free
            float f = __uint_as_float(smem[ql * 65 + e]);
            #pragma unroll
            for (int q2 = 0; q2 < CPC; ++q2) {
                float mn = fminf(bs[q2], f);
                f = fmaxf(bs[q2], f);
                bs[q2] = mn;
            }
        }
        u32* dst = ckey + ((size_t)(qb * QPB + ql) * NCHUNK + chunk) * CPC;
        #pragma unroll
        for (int i = 0; i < CPC; ++i) dst[i] = __float_as_uint(bs[i]);
    }
}

// ---------------------------------------------------------------------------
// Finalize (fused select+exact+vote): one wave per query.
//  A: 128 keys -> LDS; lane 0 selects approx-top-16 exploiting per-chunk
//     sorted order (early-out when a chunk's next key can't qualify).
//  B: lanes (cand=l>>2, part=l&3) rescore exactly in fp64.
//  C: lane 0: exact top-10 with (score,idx) tie-break (= jax top_k), majority
//     vote, ties -> LARGEST class.
// ---------------------------------------------------------------------------
__global__ __launch_bounds__(256) void knn_finalize(
    const u32* __restrict__ ckey, const float* __restrict__ x,
    const float* __restrict__ y, const int* __restrict__ labels,
    int* __restrict__ out) {
    const int lane = threadIdx.x & 63;
    const int wid  = threadIdx.x >> 6;
    const int q = blockIdx.x * 4 + wid;

    __shared__ u32 skey[4][NCAND];
    __shared__ int sidx[4][NSEL];
    __shared__ double sex[4][NSEL];

    skey[wid][lane] = ckey[(size_t)q * NCAND + lane];
    skey[wid][lane + 64] = ckey[(size_t)q * NCAND + lane + 64];
    __syncthreads();

    if (lane == 0) {
        float bs[NSEL]; int bi[NSEL];
        #pragma unroll
        for (int i = 0; i < NSEL; ++i) { bs[i] = FLT_MAX; bi[i] = 0; }
        for (int c = 0; c < NCHUNK; ++c) {
            int base = c * CPC;
            for (int j = 0; j < CPC; ++j) {
                u32 u = skey[wid][base + j];
                float f = __uint_as_float(u);
                if (f >= bs[NSEL - 1]) break;   // chunk sorted: rest can't qualify
                int id = chunk_t0(c) * 16 + (int)(u & 0xFFFu);
                #pragma unroll
                for (int pp = 0; pp < NSEL; ++pp) {
                    bool lt = f < bs[pp];
                    float nf = lt ? bs[pp] : f;  int nid = lt ? bi[pp] : id;
                    bs[pp] = lt ? f : bs[pp];    bi[pp] = lt ? id : bi[pp];
                    f = nf; id = nid;
                }
            }
        }
        #pragma unroll
        for (int i = 0; i < NSEL; ++i) sidx[wid][i] = bi[i];
    }
    __syncthreads();

    const int cand = lane >> 2;
    const int part = lane & 3;
    const int idx = sidx[wid][cand];
    const float* xr = x + (size_t)q * DIM + part * 32;
    const float* yr = y + (size_t)idx * DIM + part * 32;
    double dy2 = 0.0, dxy = 0.0;
    #pragma unroll 8
    for (int i = 0; i < 32; ++i) {
        double yy = (double)yr[i];
        dy2 = fma(yy, yy, dy2);
        dxy = fma((double)xr[i], yy, dxy);
    }
    double e = dy2 - 2.0 * dxy;
    e += __shfl_xor(e, 1, 64);
    e += __shfl_xor(e, 2, 64);
    if (part == 0) sex[wid][cand] = e;
    __syncthreads();

    if (lane == 0) {
        double tsv[KNN]; int ti[KNN];
        #pragma unroll
        for (int i = 0; i < KNN; ++i) { tsv[i] = 1e300; ti[i] = INT_MAX; }
        #pragma unroll
        for (int c = 0; c < NSEL; ++c) {
            double s = sex[wid][c];
            int id = sidx[wid][c];
            #pragma unroll
            for (int pp = 0; pp < KNN; ++pp) {
                bool lt = (s < tsv[pp]) || (s == tsv[pp] && id < ti[pp]);
                double ns = lt ? tsv[pp] : s;  int nid = lt ? ti[pp] : id;
                tsv[pp] = lt ? s : tsv[pp];    ti[pp] = lt ? id : ti[pp];
                s = ns; id = nid;
            }
        }
        int lab[KNN];
        #pragma unroll
        for (int i = 0; i < KNN; ++i) lab[i] = labels[ti[i]];
        int bestc = 0, bestn = -1;
        #pragma unroll
        for (int c = 0; c < NCLS; ++c) {
            int n = 0;
            #pragma unroll
            for (int i = 0; i < KNN; ++i) n += (lab[i] == c) ? 1 : 0;
            if (n >= bestn) { bestn = n; bestc = c; }   // >= : ties -> larger label
        }
        out[q] = bestc;
    }
}

// ---------------------------------------------------------------------------
extern "C" void kernel_launch(void* const* d_in, const int* in_sizes, int n_in,
                              void* d_out, int out_size, void* d_ws, size_t ws_size,
                              hipStream_t stream) {
    const float* x      = (const float*)d_in[0];
    const float* y      = (const float*)d_in[1];
    const int*   labels = (const int*)d_in[2];
    // d_in[3] is k == 10, baked in.

    char* ws = (char*)d_ws;
    size_t off = 0;
    u16* xb = (u16*)(ws + off);     off += (size_t)N_Q * DIM * 2;        //  2.10 MB
    u16* yb = (u16*)(ws + off);     off += (size_t)M_PTS * DIM * 2;      // 12.80 MB
    float* y2 = (float*)(ws + off); off += (size_t)M_PTS * 4 + 4096;     //  0.20 MB
    u32* ckey = (u32*)(ws + off);   off += (size_t)N_Q * NCAND * 4;      //  4.19 MB
    int* out = (int*)d_out;

    prep_kernel<<<(XN4 + YN4) / 256, 256, 0, stream>>>(
        (const float4*)x, (const float4*)y, (ushort4*)xb, (ushort4*)yb, y2);
    knn_filter<<<dim3(NCHUNK, N_Q / QPB), 256, 0, stream>>>(xb, yb, y2, ckey);
    knn_finalize<<<N_Q / 4, 256, 0, stream>>>(ckey, x, y, labels, out);
}

// Round 8
// 293.596 us; speedup vs baseline: 1.1310x; 1.0723x over previous
//
#include <hip/hip_runtime.h>
#include <float.h>
#include <limits.h>

#define N_Q 8192
#define M_PTS 50000
#define DIM 128
#define KNN 10
#define NCLS 10
#define NCHUNK 16          // 16 chunks: c<5 -> 196 tiles, else 195 (3125 total)
#define CPC 8              // candidates kept per (query, chunk)
#define NCAND (NCHUNK*CPC) // 128 candidates per query
#define NSEL 16            // exact-rescored candidates per query
#define TPL 4              // per-lane-class top depth
#define QPB 128            // queries per block (4 waves x 32)
#define XN4 (N_Q*DIM/4)    // 262144 float4 in x
#define YN4 (M_PTS*DIM/4)  // 1600000 float4 in y

typedef __attribute__((ext_vector_type(8))) short bf16x8;
typedef __attribute__((ext_vector_type(4))) float f32x4;
typedef unsigned int u32;
typedef unsigned short u16;

__device__ __forceinline__ int chunk_t0(int c) { return c * 195 + (c < 5 ? c : 5); }

__device__ __forceinline__ u16 rne_bf16(float f) {
    u32 u = __float_as_uint(f);
    u32 r = u + 0x7FFFu + ((u >> 16) & 1u);
    return (u16)(r >> 16);
}

// ---------------------------------------------------------------------------
// Prep: xb = bf16(-2x) row-major (A-frags); yt = bf16(y) PRE-SWIZZLED into
// MFMA B-fragment tile records (tile T: 4 KB; lane l=(g*16+nrow) reads its
// bf16x8 for k-block b at T*4096 + b*1024 + l*16 -> the filter's B loads are
// plain coalesced global_load_dwordx4, no LDS staging needed); y2 fp32.
// ---------------------------------------------------------------------------
__global__ __launch_bounds__(256) void prep_kernel(
    const float4* __restrict__ x4, const float4* __restrict__ y4,
    ushort4* __restrict__ xb4, u16* __restrict__ yt,
    float* __restrict__ y2) {
    int t = blockIdx.x * 256 + threadIdx.x;
    if (t < XN4) {
        float4 v = x4[t];
        ushort4 o;
        o.x = rne_bf16(-2.0f * v.x); o.y = rne_bf16(-2.0f * v.y);
        o.z = rne_bf16(-2.0f * v.z); o.w = rne_bf16(-2.0f * v.w);
        xb4[t] = o;
    } else {
        int j = t - XN4;            // float4 index into y
        int row = j >> 5;           // point 0..49999
        int d4  = j & 31;           // which float4 of the row
        float4 v = y4[j];
        ushort4 o;
        o.x = rne_bf16(v.x); o.y = rne_bf16(v.y);
        o.z = rne_bf16(v.z); o.w = rne_bf16(v.w);
        int T = row >> 4, nr = row & 15;
        int b = d4 >> 3, g = (d4 >> 1) & 3, h = d4 & 1;
        size_t dst = (size_t)T * 2048 + b * 512 + (g * 16 + nr) * 8 + h * 4; // u16 units
        *(ushort4*)(yt + dst) = o;
        float p = v.x * v.x + v.y * v.y + v.z * v.z + v.w * v.w;
        #pragma unroll
        for (int off = 16; off > 0; off >>= 1) p += __shfl_xor(p, off, 64);
        if ((j & 31) == 0) y2[row] = p;
    }
}

// ---------------------------------------------------------------------------
// Filter: NO LDS staging, NO barriers in the K-loop. Each wave streams its
// chunk's pre-swizzled tile records with 4 coalesced global_load_dwordx4
// (L1-shared across the block's 4 branchless-lockstep waves, L2-resident per
// XCD via gridDim.x=16 -> chunk%8 pinning). acc zero-init (zeros hoisted by
// compiler), y2 added at extract so the y2 load never gates the MFMA chain.
// Per score: 1 add + 1 bfi + 1 min + 3 med3. LDS only for the final merge.
// ---------------------------------------------------------------------------
__global__ __launch_bounds__(256, 4) void knn_filter(
    const u16* __restrict__ xb, const u16* __restrict__ yt,
    const float* __restrict__ y2, u32* __restrict__ ckey) {
    const int lane = threadIdx.x & 63;
    const int wid  = threadIdx.x >> 6;      // wave 0..3
    const int g    = lane >> 4;             // k-group 0..3
    const int nrow = lane & 15;             // point-in-tile (B col / C col)
    const int chunk = blockIdx.x;           // gridDim.x=16 -> XCD = chunk%8
    const int qb    = blockIdx.y;
    const int t0 = chunk_t0(chunk);
    const int tn = 195 + (chunk < 5 ? 1 : 0);
    const int p0 = t0 * 16;
    const int qw = qb * QPB + wid * 32;

    // A fragments: 2 query-sets x 4 k-blocks (k = 32*b + 8*g + e), 32 VGPRs
    bf16x8 a[2][4];
    #pragma unroll
    for (int s = 0; s < 2; ++s) {
        const u16* xr = xb + (size_t)(qw + s * 16 + nrow) * DIM + g * 8;
        #pragma unroll
        for (int b = 0; b < 4; ++b) a[s][b] = *(const bf16x8*)(xr + b * 32);
    }

    float ts[8][TPL];
    #pragma unroll
    for (int r = 0; r < 8; ++r)
        #pragma unroll
        for (int l = 0; l < TPL; ++l) ts[r][l] = FLT_MAX;

    const u16* ytp = yt + (size_t)t0 * 2048 + lane * 8;   // per-lane record ptr
    const float* y2p = y2 + p0 + nrow;

    for (int t = 0; t < tn; ++t) {
        const u16* rec = ytp + (size_t)t * 2048;
        bf16x8 b0 = *(const bf16x8*)(rec);
        bf16x8 b1 = *(const bf16x8*)(rec + 512);
        bf16x8 b2 = *(const bf16x8*)(rec + 1024);
        bf16x8 b3 = *(const bf16x8*)(rec + 1536);
        float y2n = y2p[t * 16];
        f32x4 acc0 = {0.f, 0.f, 0.f, 0.f};
        f32x4 acc1 = {0.f, 0.f, 0.f, 0.f};
        acc0 = __builtin_amdgcn_mfma_f32_16x16x32_bf16(a[0][0], b0, acc0, 0, 0, 0);
        acc0 = __builtin_amdgcn_mfma_f32_16x16x32_bf16(a[0][1], b1, acc0, 0, 0, 0);
        acc0 = __builtin_amdgcn_mfma_f32_16x16x32_bf16(a[0][2], b2, acc0, 0, 0, 0);
        acc0 = __builtin_amdgcn_mfma_f32_16x16x32_bf16(a[0][3], b3, acc0, 0, 0, 0);
        acc1 = __builtin_amdgcn_mfma_f32_16x16x32_bf16(a[1][0], b0, acc1, 0, 0, 0);
        acc1 = __builtin_amdgcn_mfma_f32_16x16x32_bf16(a[1][1], b1, acc1, 0, 0, 0);
        acc1 = __builtin_amdgcn_mfma_f32_16x16x32_bf16(a[1][2], b2, acc1, 0, 0, 0);
        acc1 = __builtin_amdgcn_mfma_f32_16x16x32_bf16(a[1][3], b3, acc1, 0, 0, 0);
        u32 rel = (u32)(t * 16) | (u32)nrow;              // < 3136, 12 bits
        #pragma unroll
        for (int i = 0; i < 4; ++i) {
            float sc = acc0[i] + y2n;
            float key = __uint_as_float((__float_as_uint(sc) & 0xFFFFF000u) | rel);
            float o0 = ts[i][0], o1 = ts[i][1], o2 = ts[i][2];
            ts[i][0] = fminf(o0, key);
            ts[i][1] = __builtin_amdgcn_fmed3f(key, o0, o1);
            ts[i][2] = __builtin_amdgcn_fmed3f(key, o1, o2);
            ts[i][3] = __builtin_amdgcn_fmed3f(key, o2, ts[i][3]);
        }
        #pragma unroll
        for (int i = 0; i < 4; ++i) {
            float sc = acc1[i] + y2n;
            float key = __uint_as_float((__float_as_uint(sc) & 0xFFFFF000u) | rel);
            float o0 = ts[4 + i][0], o1 = ts[4 + i][1], o2 = ts[4 + i][2];
            ts[4 + i][0] = fminf(o0, key);
            ts[4 + i][1] = __builtin_amdgcn_fmed3f(key, o0, o1);
            ts[4 + i][2] = __builtin_amdgcn_fmed3f(key, o1, o2);
            ts[4 + i][3] = __builtin_amdgcn_fmed3f(key, o2, ts[4 + i][3]);
        }
    }

    // ---- merge 16 lane-classes -> per-query sorted top-8 (LDS, 2 barriers) --
    __shared__ u32 smem[QPB * 65];          // 33280 B
    #pragma unroll
    for (int s = 0; s < 2; ++s)
        #pragma unroll
        for (int r = 0; r < 4; ++r) {
            int ql = wid * 32 + s * 16 + g * 4 + r;
            #pragma unroll
            for (int l = 0; l < TPL; ++l)
                smem[ql * 65 + nrow * TPL + l] = __float_as_uint(ts[s * 4 + r][l]);
        }
    __syncthreads();
    if (threadIdx.x < QPB) {
        int ql = threadIdx.x;
        float bs[CPC];
        #pragma unroll
        for (int i = 0; i < CPC; ++i) bs[i] = FLT_MAX;
        for (int e = 0; e < 16 * TPL; ++e) {      // stride-65: conflict-free
            float f = __uint_as_float(smem[ql * 65 + e]);
            #pragma unroll
            for (int q2 = 0; q2 < CPC; ++q2) {
                float mn = fminf(bs[q2], f);
                f = fmaxf(bs[q2], f);
                bs[q2] = mn;
            }
        }
        u32* dst = ckey + ((size_t)(qb * QPB + ql) * NCHUNK + chunk) * CPC;
        #pragma unroll
        for (int i = 0; i < CPC; ++i) dst[i] = __float_as_uint(bs[i]);
    }
}

// ---------------------------------------------------------------------------
// Finalize: 16 queries per block (4/wave). Select runs 4-way parallel (lanes
// 0-3 of each wave, serial bubble with sorted-chunk early-out); rescore: lane
// = qloc*16+cand does the full 128-dim fp64 dot; vote on lanes 0-3.
// ---------------------------------------------------------------------------
__global__ __launch_bounds__(256) void knn_finalize(
    const u32* __restrict__ ckey, const float* __restrict__ x,
    const float* __restrict__ y, const int* __restrict__ labels,
    int* __restrict__ out) {
    const int lane = threadIdx.x & 63;
    const int wid  = threadIdx.x >> 6;
    const int qbase = blockIdx.x * 16;

    __shared__ u32 skey[16][NCAND];
    __shared__ int sidx[16][NSEL];
    __shared__ double sex[16][NSEL];

    for (int i = threadIdx.x; i < 16 * NCAND; i += 256)
        skey[i >> 7][i & 127] = ckey[(size_t)(qbase + (i >> 7)) * NCAND + (i & 127)];
    __syncthreads();

    if (lane < 4) {                         // 4 parallel selects per wave
        int ql = wid * 4 + lane;
        float bs[NSEL]; int bi[NSEL];
        #pragma unroll
        for (int i = 0; i < NSEL; ++i) { bs[i] = FLT_MAX; bi[i] = 0; }
        for (int c = 0; c < NCHUNK; ++c) {
            int base = c * CPC;
            for (int j = 0; j < CPC; ++j) {
                u32 u = skey[ql][base + j];
                float f = __uint_as_float(u);
                if (f >= bs[NSEL - 1]) break;   // chunk sorted: rest can't qualify
                int id = chunk_t0(c) * 16 + (int)(u & 0xFFFu);
                #pragma unroll
                for (int pp = 0; pp < NSEL; ++pp) {
                    bool lt = f < bs[pp];
                    float nf = lt ? bs[pp] : f;  int nid = lt ? bi[pp] : id;
                    bs[pp] = lt ? f : bs[pp];    bi[pp] = lt ? id : bi[pp];
                    f = nf; id = nid;
                }
            }
        }
        #pragma unroll
        for (int i = 0; i < NSEL; ++i) sidx[ql][i] = bi[i];
    }
    __syncthreads();

    // exact fp64 rescore: lane -> (qloc = lane>>4, cand = lane&15)
    const int qloc = lane >> 4;
    const int cand = lane & 15;
    const int ql = wid * 4 + qloc;
    const int idx = sidx[ql][cand];
    const float4* xr = (const float4*)(x + (size_t)(qbase + ql) * DIM);
    const float4* yr = (const float4*)(y + (size_t)idx * DIM);
    double dy2 = 0.0, dxy = 0.0;
    #pragma unroll 8
    for (int i = 0; i < 32; ++i) {
        float4 yv = yr[i];
        float4 xv = xr[i];
        dy2 = fma((double)yv.x, (double)yv.x, dy2);
        dy2 = fma((double)yv.y, (double)yv.y, dy2);
        dy2 = fma((double)yv.z, (double)yv.z, dy2);
        dy2 = fma((double)yv.w, (double)yv.w, dy2);
        dxy = fma((double)xv.x, (double)yv.x, dxy);
        dxy = fma((double)xv.y, (double)yv.y, dxy);
        dxy = fma((double)xv.z, (double)yv.z, dxy);
        dxy = fma((double)xv.w, (double)yv.w, dxy);
    }
    sex[ql][cand] = dy2 - 2.0 * dxy;
    __syncthreads();

    if (lane < 4) {                         // 4 parallel votes per wave
        int ql2 = wid * 4 + lane;
        double tsv[KNN]; int ti[KNN];
        #pragma unroll
        for (int i = 0; i < KNN; ++i) { tsv[i] = 1e300; ti[i] = INT_MAX; }
        #pragma unroll
        for (int c = 0; c < NSEL; ++c) {
            double s = sex[ql2][c];
            int id = sidx[ql2][c];
            #pragma unroll
            for (int pp = 0; pp < KNN; ++pp) {
                bool lt = (s < tsv[pp]) || (s == tsv[pp] && id < ti[pp]);
                double ns = lt ? tsv[pp] : s;  int nid = lt ? ti[pp] : id;
                tsv[pp] = lt ? s : tsv[pp];    ti[pp] = lt ? id : ti[pp];
                s = ns; id = nid;
            }
        }
        int lab[KNN];
        #pragma unroll
        for (int i = 0; i < KNN; ++i) lab[i] = labels[ti[i]];
        int bestc = 0, bestn = -1;
        #pragma unroll
        for (int c = 0; c < NCLS; ++c) {
            int n = 0;
            #pragma unroll
            for (int i = 0; i < KNN; ++i) n += (lab[i] == c) ? 1 : 0;
            if (n >= bestn) { bestn = n; bestc = c; }   // >= : ties -> larger label
        }
        out[qbase + ql2] = bestc;
    }
}

// ---------------------------------------------------------------------------
extern "C" void kernel_launch(void* const* d_in, const int* in_sizes, int n_in,
                              void* d_out, int out_size, void* d_ws, size_t ws_size,
                              hipStream_t stream) {
    const float* x      = (const float*)d_in[0];
    const float* y      = (const float*)d_in[1];
    const int*   labels = (const int*)d_in[2];
    // d_in[3] is k == 10, baked in.

    char* ws = (char*)d_ws;
    size_t off = 0;
    u16* xb = (u16*)(ws + off);     off += (size_t)N_Q * DIM * 2;        //  2.10 MB
    u16* yt = (u16*)(ws + off);     off += (size_t)3125 * 4096;          // 12.80 MB (swizzled tiles)
    float* y2 = (float*)(ws + off); off += (size_t)M_PTS * 4 + 4096;     //  0.20 MB
    u32* ckey = (u32*)(ws + off);   off += (size_t)N_Q * NCAND * 4;      //  4.19 MB
    int* out = (int*)d_out;

    prep_kernel<<<(XN4 + YN4) / 256, 256, 0, stream>>>(
        (const float4*)x, (const float4*)y, (ushort4*)xb, yt, y2);
    knn_filter<<<dim3(NCHUNK, N_Q / QPB), 256, 0, stream>>>(xb, yt, y2, ckey);
    knn_finalize<<<N_Q / 16, 256, 0, stream>>>(ckey, x, y, labels, out);
}